// Round 1
// baseline (359.115 us; speedup 1.0000x reference)
//
#include <hip/hip_runtime.h>
#include <math.h>
#include <stdint.h>

// Problem constants (FPModule: knn-interpolate + 2-layer MLP)
#define Bn    4
#define Nn    2048
#define Mn    8192
#define CIN   256
#define CSKIP 128
#define HID   256
#define COUT  128

// ---------------------------------------------------------------------------
// Kernel 1: 3-NN inverse-distance interpolation.
// grid = (B*M/256) = 128 blocks x 256 threads. Each block serves 256 queries
// of ONE batch (8192/256 = 32 blocks per batch). Phase 1: per-thread query,
// scan all 2048 candidate points staged in LDS (float4: xyz + |p|^2).
// Phase 2: cooperative per-wave gather of the 3 feature rows (coalesced).
//
// Numerics: replicate reference d2 = (|q|^2 + |p|^2) - 2*dot with explicit
// __fmul_rn/__fadd_rn (no FMA contraction) so rounding noise tracks the
// reference; strict < insertion == top_k lowest-index tie-break.
// ---------------------------------------------------------------------------
__global__ __launch_bounds__(256) void knn_interp_kernel(
    const float* __restrict__ x,         // (B*N, CIN)
    const float* __restrict__ pos,       // (B*N, 3)
    const float* __restrict__ pos_skip,  // (B*M, 3)
    float* __restrict__ xi)              // (B*M, CIN) out
{
    __shared__ float4 spos[Nn];          // 32 KB
    __shared__ int    sIdx[256][3];
    __shared__ float  sW[256][4];        // w0,w1,w2,den

    const int tid = threadIdx.x;
    const int q   = blockIdx.x * 256 + tid;
    const int b   = q / Mn;              // uniform across block

    // stage this batch's candidate points (+ precomputed |p|^2)
    for (int i = tid; i < Nn; i += 256) {
        const float* p = pos + (size_t)(b * Nn + i) * 3;
        float p0 = p[0], p1 = p[1], p2 = p[2];
        float pp = __fadd_rn(__fadd_rn(__fmul_rn(p0, p0), __fmul_rn(p1, p1)),
                             __fmul_rn(p2, p2));
        spos[i] = make_float4(p0, p1, p2, pp);
    }
    __syncthreads();

    const float* qp = pos_skip + (size_t)q * 3;
    const float q0 = qp[0], q1 = qp[1], q2 = qp[2];
    const float qq = __fadd_rn(__fadd_rn(__fmul_rn(q0, q0), __fmul_rn(q1, q1)),
                               __fmul_rn(q2, q2));

    float dA = INFINITY, dB = INFINITY, dC = INFINITY;
    int   iA = 0, iB = 0, iC = 0;
    for (int p = 0; p < Nn; ++p) {
        float4 P = spos[p];   // broadcast read (all lanes same addr: free)
        float dot = __fadd_rn(__fadd_rn(__fmul_rn(q0, P.x), __fmul_rn(q1, P.y)),
                              __fmul_rn(q2, P.z));
        float d = __fsub_rn(__fadd_rn(qq, P.w), __fmul_rn(2.0f, dot));
        if (d < dC) {
            if (d < dB) {
                dC = dB; iC = iB;
                if (d < dA) { dB = dA; iB = iA; dA = d; iA = p; }
                else        { dB = d;  iB = p; }
            } else { dC = d; iC = p; }
        }
    }

    {
        float w0 = 1.0f / (fmaxf(dA, 0.0f) + 1e-16f);
        float w1 = 1.0f / (fmaxf(dB, 0.0f) + 1e-16f);
        float w2 = 1.0f / (fmaxf(dC, 0.0f) + 1e-16f);
        sIdx[tid][0] = iA; sIdx[tid][1] = iB; sIdx[tid][2] = iC;
        sW[tid][0] = w0; sW[tid][1] = w1; sW[tid][2] = w2;
        sW[tid][3] = w0 + w1 + w2;
    }
    __syncthreads();

    // Phase 2: wave w gathers for queries [w*64, w*64+64); lane covers 4 chans
    const int wave = tid >> 6, lane = tid & 63;
    const size_t xbase = (size_t)b * Nn * CIN;
    for (int j = 0; j < 64; ++j) {
        const int lq = wave * 64 + j;
        const int gq = blockIdx.x * 256 + lq;
        const int i0 = sIdx[lq][0], i1 = sIdx[lq][1], i2 = sIdx[lq][2];
        const float w0 = sW[lq][0], w1 = sW[lq][1], w2 = sW[lq][2], den = sW[lq][3];
        const float4 f0 = ((const float4*)(x + xbase + (size_t)i0 * CIN))[lane];
        const float4 f1 = ((const float4*)(x + xbase + (size_t)i1 * CIN))[lane];
        const float4 f2 = ((const float4*)(x + xbase + (size_t)i2 * CIN))[lane];
        float4 o;
        o.x = (w0 * f0.x + w1 * f1.x + w2 * f2.x) / den;
        o.y = (w0 * f0.y + w1 * f1.y + w2 * f2.y) / den;
        o.z = (w0 * f0.z + w1 * f1.z + w2 * f2.z) / den;
        o.w = (w0 * f0.w + w1 * f1.w + w2 * f2.w) / den;
        ((float4*)(xi + (size_t)gq * CIN))[lane] = o;
    }
}

// ---------------------------------------------------------------------------
// Kernel 2/3: f32 tiled GEMM, C = act(A @ W + bias).
// A is a virtual concat: col k < K0 -> A0[row*K0+k], else A1[row*(K-K0)+(k-K0)].
// 128x128 tile, BK=16, 256 threads, 8x8 micro-tile split as 4+4 rows/cols at
// +64 offset so LDS reads are stride-4 float4 (2-way bank alias = free).
// ---------------------------------------------------------------------------
template<bool RELU>
__global__ __launch_bounds__(256) void gemm128(
    const float* __restrict__ A0, const float* __restrict__ A1,
    const float* __restrict__ W,  const float* __restrict__ bias,
    float* __restrict__ C, int Ncols, int Kdim, int K0)
{
    __shared__ float As[16][128];
    __shared__ float Bs[16][128];

    const int tid = threadIdx.x;
    const long bm = (long)blockIdx.x * 128;
    const int  bn = blockIdx.y * 128;

    const int lm  = tid & 127;          // A-load row
    const int lk  = (tid >> 7) * 8;     // A-load k base (0 or 8)
    const int lnB = (tid & 31) * 4;     // B-load col
    const int lkB = tid >> 5;           // B-load k (0..7)

    const int tm = (tid & 15) * 4;      // micro-tile row base
    const int tn = (tid >> 4) * 4;      // micro-tile col base

    float acc[8][8] = {};

    for (int kt = 0; kt < Kdim; kt += 16) {
        const long arow = bm + lm;
#pragma unroll
        for (int h = 0; h < 2; ++h) {
            const int kg = kt + lk + h * 4;
            float4 a;
            if (kg < K0) a = *(const float4*)(A0 + arow * K0 + kg);
            else         a = *(const float4*)(A1 + arow * (Kdim - K0) + (kg - K0));
            As[lk + h * 4 + 0][lm] = a.x;
            As[lk + h * 4 + 1][lm] = a.y;
            As[lk + h * 4 + 2][lm] = a.z;
            As[lk + h * 4 + 3][lm] = a.w;
        }
#pragma unroll
        for (int h = 0; h < 2; ++h) {
            const int kb = lkB + h * 8;
            float4 bv = *(const float4*)(W + (long)(kt + kb) * Ncols + bn + lnB);
            *(float4*)&Bs[kb][lnB] = bv;
        }
        __syncthreads();

#pragma unroll
        for (int k = 0; k < 16; ++k) {
            const float4 a0 = *(const float4*)&As[k][tm];
            const float4 a1 = *(const float4*)&As[k][tm + 64];
            const float4 b0 = *(const float4*)&Bs[k][tn];
            const float4 b1 = *(const float4*)&Bs[k][tn + 64];
            const float av[8] = {a0.x, a0.y, a0.z, a0.w, a1.x, a1.y, a1.z, a1.w};
            const float bv[8] = {b0.x, b0.y, b0.z, b0.w, b1.x, b1.y, b1.z, b1.w};
#pragma unroll
            for (int i = 0; i < 8; ++i)
#pragma unroll
                for (int j = 0; j < 8; ++j)
                    acc[i][j] = fmaf(av[i], bv[j], acc[i][j]);
        }
        __syncthreads();
    }

    const float4 bb0 = *(const float4*)(bias + bn + tn);
    const float4 bb1 = *(const float4*)(bias + bn + tn + 64);
    const float bbv[8] = {bb0.x, bb0.y, bb0.z, bb0.w, bb1.x, bb1.y, bb1.z, bb1.w};
#pragma unroll
    for (int i = 0; i < 8; ++i) {
        const long row = bm + tm + ((i < 4) ? i : 60 + i);   // +64 block for i>=4
        float4 o0, o1;
        o0.x = acc[i][0] + bbv[0]; o0.y = acc[i][1] + bbv[1];
        o0.z = acc[i][2] + bbv[2]; o0.w = acc[i][3] + bbv[3];
        o1.x = acc[i][4] + bbv[4]; o1.y = acc[i][5] + bbv[5];
        o1.z = acc[i][6] + bbv[6]; o1.w = acc[i][7] + bbv[7];
        if (RELU) {
            o0.x = fmaxf(o0.x, 0.f); o0.y = fmaxf(o0.y, 0.f);
            o0.z = fmaxf(o0.z, 0.f); o0.w = fmaxf(o0.w, 0.f);
            o1.x = fmaxf(o1.x, 0.f); o1.y = fmaxf(o1.y, 0.f);
            o1.z = fmaxf(o1.z, 0.f); o1.w = fmaxf(o1.w, 0.f);
        }
        *(float4*)(C + row * Ncols + bn + tn)      = o0;
        *(float4*)(C + row * Ncols + bn + tn + 64) = o1;
    }
}

// ---------------------------------------------------------------------------
// Kernel 4: tail outputs — copy pos_skip, synthesize batch_skip = j / 8192.
// 131072 elements = 512 blocks x 256 threads exactly.
// ---------------------------------------------------------------------------
__global__ __launch_bounds__(256) void tail_kernel(
    const float* __restrict__ pos_skip, float* __restrict__ dst)
{
    const int i = blockIdx.x * 256 + threadIdx.x;
    const int nPos = Bn * Mn * 3;       // 98304
    if (i < nPos) {
        dst[i] = pos_skip[i];
    } else {
        const int j = i - nPos;         // 0..32767
        dst[nPos + j] = (float)(j >> 13);   // j / 8192 = batch index
    }
}

// ---------------------------------------------------------------------------
extern "C" void kernel_launch(void* const* d_in, const int* in_sizes, int n_in,
                              void* d_out, int out_size, void* d_ws, size_t ws_size,
                              hipStream_t stream)
{
    const float* x        = (const float*)d_in[0];
    const float* pos      = (const float*)d_in[1];
    const float* x_skip   = (const float*)d_in[2];
    const float* pos_skip = (const float*)d_in[3];
    const float* W1       = (const float*)d_in[4];
    const float* b1       = (const float*)d_in[5];
    const float* W2       = (const float*)d_in[6];
    const float* b2       = (const float*)d_in[7];

    float* out = (float*)d_out;                                  // (B*M, COUT) first
    float* xi  = (float*)d_ws;                                   // 32 MB
    float* h1  = (float*)((char*)d_ws + (size_t)Bn * Mn * CIN * sizeof(float)); // 32 MB

    // 1) KNN interpolate -> xi
    knn_interp_kernel<<<dim3(Bn * Mn / 256), 256, 0, stream>>>(x, pos, pos_skip, xi);

    // 2) h1 = relu([xi | x_skip] @ W1 + b1)   M=32768 K=384 N=256
    gemm128<true><<<dim3(Bn * Mn / 128, HID / 128), 256, 0, stream>>>(
        xi, x_skip, W1, b1, h1, HID, CIN + CSKIP, CIN);

    // 3) out = h1 @ W2 + b2                    M=32768 K=256 N=128
    gemm128<false><<<dim3(Bn * Mn / 128, COUT / 128), 256, 0, stream>>>(
        h1, h1, W2, b2, out, COUT, HID, HID);

    // 4) pos_skip + batch_skip passthrough outputs
    tail_kernel<<<dim3(512), 256, 0, stream>>>(
        pos_skip, out + (size_t)Bn * Mn * COUT);
}

// Round 2
// 170.840 us; speedup vs baseline: 2.1021x; 2.1021x over previous
//
#include <hip/hip_runtime.h>
#include <math.h>
#include <stdint.h>

// Problem constants (FPModule: knn-interpolate + 2-layer MLP)
#define Bn    4
#define Nn    2048
#define Mn    8192
#define CIN   256
#define CSKIP 128
#define HID   256
#define COUT  128

// ---------------------------------------------------------------------------
// Kernel 1: 3-NN inverse-distance interpolation. R2: parallelized scan.
// grid = B*M/32 = 1024 blocks x 256 threads. Each block: 32 queries of ONE
// batch. Thread layout: q_local = tid&31, chunk = tid>>5 (8 chunks x 256
// candidates). Each thread scans its 256-candidate chunk, posts a partial
// top-3; wave 0 merges the 8 partials per query in chunk order (strict <
// insert == jax top_k lowest-index tie-break). A wave's 64 lanes read only
// 2 distinct spos addresses/iter (2-way broadcast alias = free).
//
// Numerics: replicate reference d2 = (|q|^2 + |p|^2) - 2*dot with explicit
// __fmul_rn/__fadd_rn (no FMA contraction) so rounding noise tracks the
// reference.
// ---------------------------------------------------------------------------
__global__ __launch_bounds__(256) void knn_interp_kernel(
    const float* __restrict__ x,         // (B*N, CIN)
    const float* __restrict__ pos,       // (B*N, 3)
    const float* __restrict__ pos_skip,  // (B*M, 3)
    float* __restrict__ xi)              // (B*M, CIN) out
{
    __shared__ float4 spos[Nn];          // 32 KB
    __shared__ float  sPd[32][8][3];     // partial top-3 dists
    __shared__ int    sPi[32][8][3];     // partial top-3 indices
    __shared__ int    sIdx[32][3];
    __shared__ float  sW[32][4];         // w0,w1,w2,den

    const int tid    = threadIdx.x;
    const int qloc   = tid & 31;
    const int chunk  = tid >> 5;
    const int blockQ = blockIdx.x * 32;
    const int b      = blockQ / Mn;      // uniform across block (256 blocks/batch)

    // stage this batch's candidate points (+ precomputed |p|^2)
    for (int i = tid; i < Nn; i += 256) {
        const float* p = pos + (size_t)(b * Nn + i) * 3;
        float p0 = p[0], p1 = p[1], p2 = p[2];
        float pp = __fadd_rn(__fadd_rn(__fmul_rn(p0, p0), __fmul_rn(p1, p1)),
                             __fmul_rn(p2, p2));
        spos[i] = make_float4(p0, p1, p2, pp);
    }
    __syncthreads();

    const int q = blockQ + qloc;
    const float* qp = pos_skip + (size_t)q * 3;
    const float q0 = qp[0], q1 = qp[1], q2 = qp[2];
    const float qq = __fadd_rn(__fadd_rn(__fmul_rn(q0, q0), __fmul_rn(q1, q1)),
                               __fmul_rn(q2, q2));

    float dA = INFINITY, dB = INFINITY, dC = INFINITY;
    int   iA = 0, iB = 0, iC = 0;
    const int base = chunk * 256;
#pragma unroll 4
    for (int j = 0; j < 256; ++j) {
        float4 P = spos[base + j];
        float dot = __fadd_rn(__fadd_rn(__fmul_rn(q0, P.x), __fmul_rn(q1, P.y)),
                              __fmul_rn(q2, P.z));
        float d = __fsub_rn(__fadd_rn(qq, P.w), __fmul_rn(2.0f, dot));
        if (d < dC) {
            if (d < dB) {
                dC = dB; iC = iB;
                if (d < dA) { dB = dA; iB = iA; dA = d; iA = base + j; }
                else        { dB = d;  iB = base + j; }
            } else { dC = d; iC = base + j; }
        }
    }
    sPd[qloc][chunk][0] = dA; sPd[qloc][chunk][1] = dB; sPd[qloc][chunk][2] = dC;
    sPi[qloc][chunk][0] = iA; sPi[qloc][chunk][1] = iB; sPi[qloc][chunk][2] = iC;
    __syncthreads();

    // merge 8 partial lists per query (threads 0..31), chunk order = index order
    if (tid < 32) {
        float mA = INFINITY, mB = INFINITY, mC = INFINITY;
        int   jA = 0, jB = 0, jC = 0;
#pragma unroll
        for (int c = 0; c < 8; ++c) {
#pragma unroll
            for (int s = 0; s < 3; ++s) {
                float d = sPd[tid][c][s];
                int   i = sPi[tid][c][s];
                if (d < mC) {
                    if (d < mB) {
                        mC = mB; jC = jB;
                        if (d < mA) { mB = mA; jB = jA; mA = d; jA = i; }
                        else        { mB = d;  jB = i; }
                    } else { mC = d; jC = i; }
                }
            }
        }
        float w0 = 1.0f / (fmaxf(mA, 0.0f) + 1e-16f);
        float w1 = 1.0f / (fmaxf(mB, 0.0f) + 1e-16f);
        float w2 = 1.0f / (fmaxf(mC, 0.0f) + 1e-16f);
        sIdx[tid][0] = jA; sIdx[tid][1] = jB; sIdx[tid][2] = jC;
        sW[tid][0] = w0; sW[tid][1] = w1; sW[tid][2] = w2;
        sW[tid][3] = w0 + w1 + w2;
    }
    __syncthreads();

    // gather: wave w handles queries [w*8, w*8+8); lane covers 4 channels
    const int wave = tid >> 6, lane = tid & 63;
    const size_t xbase = (size_t)b * Nn * CIN;
    for (int j = 0; j < 8; ++j) {
        const int lq = wave * 8 + j;
        const int gq = blockQ + lq;
        const int i0 = sIdx[lq][0], i1 = sIdx[lq][1], i2 = sIdx[lq][2];
        const float w0 = sW[lq][0], w1 = sW[lq][1], w2 = sW[lq][2], den = sW[lq][3];
        const float4 f0 = ((const float4*)(x + xbase + (size_t)i0 * CIN))[lane];
        const float4 f1 = ((const float4*)(x + xbase + (size_t)i1 * CIN))[lane];
        const float4 f2 = ((const float4*)(x + xbase + (size_t)i2 * CIN))[lane];
        float4 o;
        o.x = (w0 * f0.x + w1 * f1.x + w2 * f2.x) / den;
        o.y = (w0 * f0.y + w1 * f1.y + w2 * f2.y) / den;
        o.z = (w0 * f0.z + w1 * f1.z + w2 * f2.z) / den;
        o.w = (w0 * f0.w + w1 * f1.w + w2 * f2.w) / den;
        ((float4*)(xi + (size_t)gq * CIN))[lane] = o;
    }
}

// ---------------------------------------------------------------------------
// Kernel 2/3: f32 tiled GEMM, C = act(A @ W + bias).
// A is a virtual concat: col k < K0 -> A0[row*K0+k], else A1[row*(K-K0)+(k-K0)].
// 128x128 tile, BK=16, 256 threads, 8x8 micro-tile split as 4+4 rows/cols at
// +64 offset so LDS reads are stride-4 float4 (2-way bank alias = free).
// ---------------------------------------------------------------------------
template<bool RELU>
__global__ __launch_bounds__(256) void gemm128(
    const float* __restrict__ A0, const float* __restrict__ A1,
    const float* __restrict__ W,  const float* __restrict__ bias,
    float* __restrict__ C, int Ncols, int Kdim, int K0)
{
    __shared__ float As[16][128];
    __shared__ float Bs[16][128];

    const int tid = threadIdx.x;
    const long bm = (long)blockIdx.x * 128;
    const int  bn = blockIdx.y * 128;

    const int lm  = tid & 127;          // A-load row
    const int lk  = (tid >> 7) * 8;     // A-load k base (0 or 8)
    const int lnB = (tid & 31) * 4;     // B-load col
    const int lkB = tid >> 5;           // B-load k (0..7)

    const int tm = (tid & 15) * 4;      // micro-tile row base
    const int tn = (tid >> 4) * 4;      // micro-tile col base

    float acc[8][8] = {};

    for (int kt = 0; kt < Kdim; kt += 16) {
        const long arow = bm + lm;
#pragma unroll
        for (int h = 0; h < 2; ++h) {
            const int kg = kt + lk + h * 4;
            float4 a;
            if (kg < K0) a = *(const float4*)(A0 + arow * K0 + kg);
            else         a = *(const float4*)(A1 + arow * (Kdim - K0) + (kg - K0));
            As[lk + h * 4 + 0][lm] = a.x;
            As[lk + h * 4 + 1][lm] = a.y;
            As[lk + h * 4 + 2][lm] = a.z;
            As[lk + h * 4 + 3][lm] = a.w;
        }
#pragma unroll
        for (int h = 0; h < 2; ++h) {
            const int kb = lkB + h * 8;
            float4 bv = *(const float4*)(W + (long)(kt + kb) * Ncols + bn + lnB);
            *(float4*)&Bs[kb][lnB] = bv;
        }
        __syncthreads();

#pragma unroll
        for (int k = 0; k < 16; ++k) {
            const float4 a0 = *(const float4*)&As[k][tm];
            const float4 a1 = *(const float4*)&As[k][tm + 64];
            const float4 b0 = *(const float4*)&Bs[k][tn];
            const float4 b1 = *(const float4*)&Bs[k][tn + 64];
            const float av[8] = {a0.x, a0.y, a0.z, a0.w, a1.x, a1.y, a1.z, a1.w};
            const float bv[8] = {b0.x, b0.y, b0.z, b0.w, b1.x, b1.y, b1.z, b1.w};
#pragma unroll
            for (int i = 0; i < 8; ++i)
#pragma unroll
                for (int j = 0; j < 8; ++j)
                    acc[i][j] = fmaf(av[i], bv[j], acc[i][j]);
        }
        __syncthreads();
    }

    const float4 bb0 = *(const float4*)(bias + bn + tn);
    const float4 bb1 = *(const float4*)(bias + bn + tn + 64);
    const float bbv[8] = {bb0.x, bb0.y, bb0.z, bb0.w, bb1.x, bb1.y, bb1.z, bb1.w};
#pragma unroll
    for (int i = 0; i < 8; ++i) {
        const long row = bm + tm + ((i < 4) ? i : 60 + i);   // +64 block for i>=4
        float4 o0, o1;
        o0.x = acc[i][0] + bbv[0]; o0.y = acc[i][1] + bbv[1];
        o0.z = acc[i][2] + bbv[2]; o0.w = acc[i][3] + bbv[3];
        o1.x = acc[i][4] + bbv[4]; o1.y = acc[i][5] + bbv[5];
        o1.z = acc[i][6] + bbv[6]; o1.w = acc[i][7] + bbv[7];
        if (RELU) {
            o0.x = fmaxf(o0.x, 0.f); o0.y = fmaxf(o0.y, 0.f);
            o0.z = fmaxf(o0.z, 0.f); o0.w = fmaxf(o0.w, 0.f);
            o1.x = fmaxf(o1.x, 0.f); o1.y = fmaxf(o1.y, 0.f);
            o1.z = fmaxf(o1.z, 0.f); o1.w = fmaxf(o1.w, 0.f);
        }
        *(float4*)(C + row * Ncols + bn + tn)      = o0;
        *(float4*)(C + row * Ncols + bn + tn + 64) = o1;
    }
}

// ---------------------------------------------------------------------------
// Kernel 4: tail outputs — copy pos_skip, synthesize batch_skip = j / 8192.
// 131072 elements = 512 blocks x 256 threads exactly.
// ---------------------------------------------------------------------------
__global__ __launch_bounds__(256) void tail_kernel(
    const float* __restrict__ pos_skip, float* __restrict__ dst)
{
    const int i = blockIdx.x * 256 + threadIdx.x;
    const int nPos = Bn * Mn * 3;       // 98304
    if (i < nPos) {
        dst[i] = pos_skip[i];
    } else {
        const int j = i - nPos;         // 0..32767
        dst[nPos + j] = (float)(j >> 13);   // j / 8192 = batch index
    }
}

// ---------------------------------------------------------------------------
extern "C" void kernel_launch(void* const* d_in, const int* in_sizes, int n_in,
                              void* d_out, int out_size, void* d_ws, size_t ws_size,
                              hipStream_t stream)
{
    const float* x        = (const float*)d_in[0];
    const float* pos      = (const float*)d_in[1];
    const float* x_skip   = (const float*)d_in[2];
    const float* pos_skip = (const float*)d_in[3];
    const float* W1       = (const float*)d_in[4];
    const float* b1       = (const float*)d_in[5];
    const float* W2       = (const float*)d_in[6];
    const float* b2       = (const float*)d_in[7];

    float* out = (float*)d_out;                                  // (B*M, COUT) first
    float* xi  = (float*)d_ws;                                   // 32 MB
    float* h1  = (float*)((char*)d_ws + (size_t)Bn * Mn * CIN * sizeof(float)); // 32 MB

    // 1) KNN interpolate -> xi  (1024 blocks: 32 queries/block, 8-way split scan)
    knn_interp_kernel<<<dim3(Bn * Mn / 32), 256, 0, stream>>>(x, pos, pos_skip, xi);

    // 2) h1 = relu([xi | x_skip] @ W1 + b1)   M=32768 K=384 N=256
    gemm128<true><<<dim3(Bn * Mn / 128, HID / 128), 256, 0, stream>>>(
        xi, x_skip, W1, b1, h1, HID, CIN + CSKIP, CIN);

    // 3) out = h1 @ W2 + b2                    M=32768 K=256 N=128
    gemm128<false><<<dim3(Bn * Mn / 128, COUT / 128), 256, 0, stream>>>(
        h1, h1, W2, b2, out, COUT, HID, HID);

    // 4) pos_skip + batch_skip passthrough outputs
    tail_kernel<<<dim3(512), 256, 0, stream>>>(
        pos_skip, out + (size_t)Bn * Mn * COUT);
}

// Round 3
// 85.866 us; speedup vs baseline: 4.1823x; 1.9896x over previous
//
#include <hip/hip_runtime.h>
#include <math.h>
#include <stdint.h>

// Problem constants (FPModule: knn-interpolate + 2-layer MLP)
#define Bn    4
#define Nn    2048
#define Mn    8192
#define CIN   256
#define CSKIP 128
#define HID   256
#define COUT  128
#define KTOT  384   // CIN + CSKIP

typedef short bf16x8 __attribute__((ext_vector_type(8)));
typedef float f32x16 __attribute__((ext_vector_type(16)));

__device__ __forceinline__ ushort f2bf(float f) {
    union { float f; unsigned u; } v; v.f = f;
    return (ushort)((v.u + 0x7fffu + ((v.u >> 16) & 1u)) >> 16);   // RNE
}

// ---------------------------------------------------------------------------
// Kernel 0: weight/skip prep.
//  - Abig[:, 256:384] = bf16(x_skip)                (4096 blocks)
//  - W1T[n][k] = bf16(W1[k][n])  (256 x 384)        (96 blocks)
//  - W2T[n][k] = bf16(W2[k][n])  (128 x 256)        (32 blocks)
// ---------------------------------------------------------------------------
__global__ __launch_bounds__(256) void convert_kernel(
    const float* __restrict__ xs, const float* __restrict__ W1,
    const float* __restrict__ W2, ushort* __restrict__ Abig,
    ushort* __restrict__ W1T, ushort* __restrict__ W2T)
{
    const int bid = blockIdx.x, tid = threadIdx.x;
    if (bid < 4096) {
        const int q   = bid * 256 + tid;        // quad over 32768x128
        const int row = q >> 5;
        const int cq  = (q & 31) * 4;
        const float4 v = *(const float4*)(xs + (size_t)row * CSKIP + cq);
        ushort4 o; o.x = f2bf(v.x); o.y = f2bf(v.y); o.z = f2bf(v.z); o.w = f2bf(v.w);
        *(ushort4*)(Abig + (size_t)row * KTOT + CIN + cq) = o;
    } else if (bid < 4096 + 96) {
        const int q  = (bid - 4096) * 256 + tid;   // 24576 quads: n*96 + kq
        const int n  = q / 96;
        const int kq = (q % 96) * 4;
        ushort4 o;
        o.x = f2bf(W1[(size_t)(kq + 0) * HID + n]);
        o.y = f2bf(W1[(size_t)(kq + 1) * HID + n]);
        o.z = f2bf(W1[(size_t)(kq + 2) * HID + n]);
        o.w = f2bf(W1[(size_t)(kq + 3) * HID + n]);
        *(ushort4*)(W1T + (size_t)n * KTOT + kq) = o;
    } else {
        const int q  = (bid - 4192) * 256 + tid;   // 8192 quads: n*64 + kq
        const int n  = q >> 6;
        const int kq = (q & 63) * 4;
        ushort4 o;
        o.x = f2bf(W2[(size_t)(kq + 0) * COUT + n]);
        o.y = f2bf(W2[(size_t)(kq + 1) * COUT + n]);
        o.z = f2bf(W2[(size_t)(kq + 2) * COUT + n]);
        o.w = f2bf(W2[(size_t)(kq + 3) * COUT + n]);
        *(ushort4*)(W2T + (size_t)n * HID + kq) = o;
    }
}

// ---------------------------------------------------------------------------
// Kernel 1: 3-NN inverse-distance interpolation -> bf16 into Abig[:, 0:256].
// Same structure as R2 (1024 blocks x 256 thr, 8-way split scan); numerics
// replicate reference d2 formula with explicit _rn ops; strict < insertion
// == jax top_k lowest-index tie-break.
// ---------------------------------------------------------------------------
__global__ __launch_bounds__(256) void knn_interp_kernel(
    const float* __restrict__ x,         // (B*N, CIN)
    const float* __restrict__ pos,       // (B*N, 3)
    const float* __restrict__ pos_skip,  // (B*M, 3)
    ushort* __restrict__ Abig)           // (B*M, KTOT) bf16, cols 0..255
{
    __shared__ float4 spos[Nn];          // 32 KB
    __shared__ float  sPd[32][8][3];
    __shared__ int    sPi[32][8][3];
    __shared__ int    sIdx[32][3];
    __shared__ float  sW[32][4];

    const int tid    = threadIdx.x;
    const int qloc   = tid & 31;
    const int chunk  = tid >> 5;
    const int blockQ = blockIdx.x * 32;
    const int b      = blockQ / Mn;

    for (int i = tid; i < Nn; i += 256) {
        const float* p = pos + (size_t)(b * Nn + i) * 3;
        float p0 = p[0], p1 = p[1], p2 = p[2];
        float pp = __fadd_rn(__fadd_rn(__fmul_rn(p0, p0), __fmul_rn(p1, p1)),
                             __fmul_rn(p2, p2));
        spos[i] = make_float4(p0, p1, p2, pp);
    }
    __syncthreads();

    const int q = blockQ + qloc;
    const float* qp = pos_skip + (size_t)q * 3;
    const float q0 = qp[0], q1 = qp[1], q2 = qp[2];
    const float qq = __fadd_rn(__fadd_rn(__fmul_rn(q0, q0), __fmul_rn(q1, q1)),
                               __fmul_rn(q2, q2));

    float dA = INFINITY, dB = INFINITY, dC = INFINITY;
    int   iA = 0, iB = 0, iC = 0;
    const int base = chunk * 256;
#pragma unroll 4
    for (int j = 0; j < 256; ++j) {
        float4 P = spos[base + j];
        float dot = __fadd_rn(__fadd_rn(__fmul_rn(q0, P.x), __fmul_rn(q1, P.y)),
                              __fmul_rn(q2, P.z));
        float d = __fsub_rn(__fadd_rn(qq, P.w), __fmul_rn(2.0f, dot));
        if (d < dC) {
            if (d < dB) {
                dC = dB; iC = iB;
                if (d < dA) { dB = dA; iB = iA; dA = d; iA = base + j; }
                else        { dB = d;  iB = base + j; }
            } else { dC = d; iC = base + j; }
        }
    }
    sPd[qloc][chunk][0] = dA; sPd[qloc][chunk][1] = dB; sPd[qloc][chunk][2] = dC;
    sPi[qloc][chunk][0] = iA; sPi[qloc][chunk][1] = iB; sPi[qloc][chunk][2] = iC;
    __syncthreads();

    if (tid < 32) {
        float mA = INFINITY, mB = INFINITY, mC = INFINITY;
        int   jA = 0, jB = 0, jC = 0;
#pragma unroll
        for (int c = 0; c < 8; ++c) {
#pragma unroll
            for (int s = 0; s < 3; ++s) {
                float d = sPd[tid][c][s];
                int   i = sPi[tid][c][s];
                if (d < mC) {
                    if (d < mB) {
                        mC = mB; jC = jB;
                        if (d < mA) { mB = mA; jB = jA; mA = d; jA = i; }
                        else        { mB = d;  jB = i; }
                    } else { mC = d; jC = i; }
                }
            }
        }
        float w0 = 1.0f / (fmaxf(mA, 0.0f) + 1e-16f);
        float w1 = 1.0f / (fmaxf(mB, 0.0f) + 1e-16f);
        float w2 = 1.0f / (fmaxf(mC, 0.0f) + 1e-16f);
        sIdx[tid][0] = jA; sIdx[tid][1] = jB; sIdx[tid][2] = jC;
        sW[tid][0] = w0; sW[tid][1] = w1; sW[tid][2] = w2;
        sW[tid][3] = w0 + w1 + w2;
    }
    __syncthreads();

    const int wave = tid >> 6, lane = tid & 63;
    const size_t xbase = (size_t)b * Nn * CIN;
    for (int j = 0; j < 8; ++j) {
        const int lq = wave * 8 + j;
        const int gq = blockQ + lq;
        const int i0 = sIdx[lq][0], i1 = sIdx[lq][1], i2 = sIdx[lq][2];
        const float w0 = sW[lq][0], w1 = sW[lq][1], w2 = sW[lq][2], den = sW[lq][3];
        const float4 f0 = ((const float4*)(x + xbase + (size_t)i0 * CIN))[lane];
        const float4 f1 = ((const float4*)(x + xbase + (size_t)i1 * CIN))[lane];
        const float4 f2 = ((const float4*)(x + xbase + (size_t)i2 * CIN))[lane];
        ushort4 ov;
        ov.x = f2bf((w0 * f0.x + w1 * f1.x + w2 * f2.x) / den);
        ov.y = f2bf((w0 * f0.y + w1 * f1.y + w2 * f2.y) / den);
        ov.z = f2bf((w0 * f0.z + w1 * f1.z + w2 * f2.z) / den);
        ov.w = f2bf((w0 * f0.w + w1 * f1.w + w2 * f2.w) / den);
        *(ushort4*)(Abig + (size_t)gq * KTOT + lane * 4) = ov;
    }
}

// ---------------------------------------------------------------------------
// Kernel 2: fused MLP via bf16 MFMA (32x32x16), f32 accum.
// Block = 128 rows, 256 thr (4 waves as 2x2). Hidden dim processed in two
// 128-col halves; layer-2 accumulator persists in regs across halves.
// LDS 48KB: Ast[128][32] + Bst[128][32] (XOR-swizzled 16B slots, bank-
// balanced) + Hs[128][128] bf16 (slot ^ (row&7) swizzle).
// Staging: reg-staged (global->reg issued early, ds_write after barrier:
// T14 split so HBM latency hides under MFMA).
// ---------------------------------------------------------------------------
__global__ __launch_bounds__(256, 1) void mlp_fused(
    const ushort* __restrict__ Abig,   // [32768][384] bf16
    const ushort* __restrict__ W1T,    // [256][384] bf16
    const float*  __restrict__ b1,
    const ushort* __restrict__ W2T,    // [128][256] bf16
    const float*  __restrict__ b2,
    float* __restrict__ out)           // [32768][128] f32
{
    __shared__ ushort Ast[128 * 32];   // 8 KB
    __shared__ ushort Bst[128 * 32];   // 8 KB
    __shared__ ushort Hs [128 * 128];  // 32 KB

    const int tid  = threadIdx.x;
    const int wave = tid >> 6, lane = tid & 63;
    const int wr = wave >> 1, wc = wave & 1;      // 2x2 wave grid
    const int l31 = lane & 31, kc0 = lane >> 5;   // MFMA k-half
    const long rowbase = (long)blockIdx.x * 128;

    // staging: 512 chunks of 16B per 8KB tile; thread owns chunks tid, tid+256
    const int sr0 = tid >> 2;          // row of chunk tid (row+64 for chunk tid+256)
    const int ss0 = tid & 3;           // 16B slot
    const int ssw = (ss0 ^ (sr0 & 3)); // swizzled slot (same for row+64)

    f32x16 acc2[2][2];
#pragma unroll
    for (int i = 0; i < 2; ++i)
#pragma unroll
        for (int j = 0; j < 2; ++j)
#pragma unroll
            for (int e = 0; e < 16; ++e) acc2[i][j][e] = 0.0f;

    for (int nh = 0; nh < 2; ++nh) {
        f32x16 acc1[2][2];
#pragma unroll
        for (int i = 0; i < 2; ++i)
#pragma unroll
            for (int j = 0; j < 2; ++j)
#pragma unroll
                for (int e = 0; e < 16; ++e) acc1[i][j][e] = 0.0f;

        const ushort* Ab = Abig + (size_t)rowbase * KTOT;
        const ushort* Wb = W1T + (size_t)(nh * 128) * KTOT;

        uint4 ra0, ra1, rb0, rb1;
        // prologue: load tile 0
        ra0 = *(const uint4*)(Ab + (size_t)sr0 * KTOT + ss0 * 8);
        ra1 = *(const uint4*)(Ab + (size_t)(sr0 + 64) * KTOT + ss0 * 8);
        rb0 = *(const uint4*)(Wb + (size_t)sr0 * KTOT + ss0 * 8);
        rb1 = *(const uint4*)(Wb + (size_t)(sr0 + 64) * KTOT + ss0 * 8);

        for (int t = 0; t < 12; ++t) {
            __syncthreads();   // previous compute done reading Ast/Bst
            *(uint4*)&Ast[sr0 * 32 + (ssw << 3)]        = ra0;
            *(uint4*)&Ast[(sr0 + 64) * 32 + (ssw << 3)] = ra1;
            *(uint4*)&Bst[sr0 * 32 + (ssw << 3)]        = rb0;
            *(uint4*)&Bst[(sr0 + 64) * 32 + (ssw << 3)] = rb1;
            __syncthreads();
            if (t < 11) {      // issue next tile loads early (hide under MFMA)
                const int kt = (t + 1) * 32;
                ra0 = *(const uint4*)(Ab + (size_t)sr0 * KTOT + kt + ss0 * 8);
                ra1 = *(const uint4*)(Ab + (size_t)(sr0 + 64) * KTOT + kt + ss0 * 8);
                rb0 = *(const uint4*)(Wb + (size_t)sr0 * KTOT + kt + ss0 * 8);
                rb1 = *(const uint4*)(Wb + (size_t)(sr0 + 64) * KTOT + kt + ss0 * 8);
            }
#pragma unroll
            for (int s = 0; s < 2; ++s) {
                bf16x8 af[2], bq[2];
#pragma unroll
                for (int mf = 0; mf < 2; ++mf) {
                    const int r = wr * 64 + mf * 32 + l31;
                    af[mf] = *(const bf16x8*)&Ast[r * 32 + ((((s << 1) | kc0) ^ (r & 3)) << 3)];
                }
#pragma unroll
                for (int nf = 0; nf < 2; ++nf) {
                    const int rn = wc * 64 + nf * 32 + l31;
                    bq[nf] = *(const bf16x8*)&Bst[rn * 32 + ((((s << 1) | kc0) ^ (rn & 3)) << 3)];
                }
#pragma unroll
                for (int mf = 0; mf < 2; ++mf)
#pragma unroll
                    for (int nf = 0; nf < 2; ++nf)
                        acc1[mf][nf] = __builtin_amdgcn_mfma_f32_32x32x16_bf16(
                            af[mf], bq[nf], acc1[mf][nf], 0, 0, 0);
            }
        }

        // h = relu(acc1 + b1) -> Hs (bf16, swizzled); each wave writes its own
        // row/col quadrant, no overlap.
#pragma unroll
        for (int mf = 0; mf < 2; ++mf)
#pragma unroll
            for (int nf = 0; nf < 2; ++nf) {
                const int col = wc * 64 + nf * 32 + l31;      // 0..127 (half-local)
                const float b1v = b1[nh * 128 + col];
#pragma unroll
                for (int e = 0; e < 16; ++e) {
                    const int rl = wr * 64 + mf * 32 + (e & 3) + ((e >> 2) << 3) + (kc0 << 2);
                    const float hv = fmaxf(acc1[mf][nf][e] + b1v, 0.0f);
                    Hs[rl * 128 + (((col >> 3) ^ (rl & 7)) << 3) + (col & 7)] = f2bf(hv);
                }
            }
        __syncthreads();   // Hs visible; all waves past layer-1 reads of Bst

        // ---- layer 2: out += Hs(half) @ W2T rows, k = nh*128 .. +128 ----
        uint4 rw0, rw1;
        rw0 = *(const uint4*)(W2T + (size_t)sr0 * HID + nh * 128 + ss0 * 8);
        rw1 = *(const uint4*)(W2T + (size_t)(sr0 + 64) * HID + nh * 128 + ss0 * 8);

        for (int t = 0; t < 4; ++t) {
            __syncthreads();
            *(uint4*)&Bst[sr0 * 32 + (ssw << 3)]        = rw0;
            *(uint4*)&Bst[(sr0 + 64) * 32 + (ssw << 3)] = rw1;
            __syncthreads();
            if (t < 3) {
                const int kt = nh * 128 + (t + 1) * 32;
                rw0 = *(const uint4*)(W2T + (size_t)sr0 * HID + kt + ss0 * 8);
                rw1 = *(const uint4*)(W2T + (size_t)(sr0 + 64) * HID + kt + ss0 * 8);
            }
#pragma unroll
            for (int s = 0; s < 2; ++s) {
                bf16x8 af[2], bq[2];
#pragma unroll
                for (int mf = 0; mf < 2; ++mf) {
                    const int r  = wr * 64 + mf * 32 + l31;
                    const int kc = (t << 2) + (s << 1) + kc0;   // 16B slot in Hs row
                    af[mf] = *(const bf16x8*)&Hs[r * 128 + ((kc ^ (r & 7)) << 3)];
                }
#pragma unroll
                for (int nf = 0; nf < 2; ++nf) {
                    const int rn = wc * 64 + nf * 32 + l31;
                    bq[nf] = *(const bf16x8*)&Bst[rn * 32 + ((((s << 1) | kc0) ^ (rn & 3)) << 3)];
                }
#pragma unroll
                for (int mf = 0; mf < 2; ++mf)
#pragma unroll
                    for (int nf = 0; nf < 2; ++nf)
                        acc2[mf][nf] = __builtin_amdgcn_mfma_f32_32x32x16_bf16(
                            af[mf], bq[nf], acc2[mf][nf], 0, 0, 0);
            }
        }
        __syncthreads();   // Bst/Hs safe to reuse next half
    }

    // epilogue: out = acc2 + b2
#pragma unroll
    for (int mf = 0; mf < 2; ++mf)
#pragma unroll
        for (int nf = 0; nf < 2; ++nf) {
            const int col = wc * 64 + nf * 32 + l31;
            const float b2v = b2[col];
#pragma unroll
            for (int e = 0; e < 16; ++e) {
                const int rl = wr * 64 + mf * 32 + (e & 3) + ((e >> 2) << 3) + (kc0 << 2);
                out[(rowbase + rl) * COUT + col] = acc2[mf][nf][e] + b2v;
            }
        }
}

// ---------------------------------------------------------------------------
// Kernel 3: tail outputs — copy pos_skip, synthesize batch_skip.
// ---------------------------------------------------------------------------
__global__ __launch_bounds__(256) void tail_kernel(
    const float* __restrict__ pos_skip, float* __restrict__ dst)
{
    const int i = blockIdx.x * 256 + threadIdx.x;
    const int nPos = Bn * Mn * 3;       // 98304
    if (i < nPos) {
        dst[i] = pos_skip[i];
    } else {
        const int j = i - nPos;         // 0..32767
        dst[nPos + j] = (float)(j >> 13);
    }
}

// ---------------------------------------------------------------------------
extern "C" void kernel_launch(void* const* d_in, const int* in_sizes, int n_in,
                              void* d_out, int out_size, void* d_ws, size_t ws_size,
                              hipStream_t stream)
{
    const float* x        = (const float*)d_in[0];
    const float* pos      = (const float*)d_in[1];
    const float* x_skip   = (const float*)d_in[2];
    const float* pos_skip = (const float*)d_in[3];
    const float* W1       = (const float*)d_in[4];
    const float* b1       = (const float*)d_in[5];
    const float* W2       = (const float*)d_in[6];
    const float* b2       = (const float*)d_in[7];

    float* out = (float*)d_out;

    // workspace: Abig (24MB) | W1T (192KB) | W2T (64KB)
    ushort* Abig = (ushort*)d_ws;
    ushort* W1T  = (ushort*)((char*)d_ws + (size_t)Bn * Mn * KTOT * 2);
    ushort* W2T  = (ushort*)((char*)W1T + (size_t)HID * KTOT * 2);

    // 0) prep: x_skip -> Abig cols 256:384, W1T/W2T transposed bf16
    convert_kernel<<<dim3(4096 + 96 + 32), 256, 0, stream>>>(
        x_skip, W1, W2, Abig, W1T, W2T);

    // 1) KNN interpolate -> Abig cols 0:256 (bf16)
    knn_interp_kernel<<<dim3(Bn * Mn / 32), 256, 0, stream>>>(x, pos, pos_skip, Abig);

    // 2) fused MLP: out = (relu([xi|x_skip] @ W1 + b1)) @ W2 + b2
    mlp_fused<<<dim3(Bn * Mn / 128), 256, 0, stream>>>(
        Abig, W1T, b1, W2T, b2, out);

    // 3) pos_skip + batch_skip passthrough
    tail_kernel<<<dim3(512), 256, 0, stream>>>(
        pos_skip, out + (size_t)Bn * Mn * COUT);
}

// Round 4
// 77.231 us; speedup vs baseline: 4.6499x; 1.1118x over previous
//
#include <hip/hip_runtime.h>
#include <math.h>
#include <stdint.h>

// Problem constants (FPModule: knn-interpolate + 2-layer MLP)
#define Bn    4
#define Nn    2048
#define Mn    8192
#define CIN   256
#define CSKIP 128
#define HID   256
#define COUT  128
#define KTOT  384   // CIN + CSKIP

typedef short bf16x8 __attribute__((ext_vector_type(8)));
typedef float f32x16 __attribute__((ext_vector_type(16)));

__device__ __forceinline__ ushort f2bf(float f) {
    union { float f; unsigned u; } v; v.f = f;
    return (ushort)((v.u + 0x7fffu + ((v.u >> 16) & 1u)) >> 16);   // RNE
}

// ---------------------------------------------------------------------------
// Kernel 1 (fused front): block roles by blockIdx.x:
//   [0,1024)      KNN: 32 queries/block, 8-way split scan, branchless top-3.
//   [1024,5120)   Abig[:,256:384] = bf16(x_skip)
//   [5120,5216)   W1T[n][k] = bf16(W1[k][n])
//   [5216,5248)   W2T[n][k] = bf16(W2[k][n])
//   [5248,5760)   tail: copy pos_skip + synthesize batch_skip into d_out
//
// KNN numerics: spos holds (2px,2py,2pz,pp). dot2 = ((q0*2px + q1*2py) + q2*2pz)
// is BIT-IDENTICAL to 2*dot of the reference (x2 is exact, rounding commutes
// with exact power-of-2 scaling), so d = (qq+pp) - dot2 matches the reference
// d2 exactly. Branchless cndmask insert == sequential strict-< insert ==
// jax top_k lowest-index tie-break.
// ---------------------------------------------------------------------------
__global__ __launch_bounds__(256) void fused_front(
    const float* __restrict__ x,         // (B*N, CIN)
    const float* __restrict__ pos,       // (B*N, 3)
    const float* __restrict__ xs,        // (B*M, CSKIP)
    const float* __restrict__ pos_skip,  // (B*M, 3)
    const float* __restrict__ W1, const float* __restrict__ W2,
    ushort* __restrict__ Abig,           // (B*M, KTOT) bf16
    ushort* __restrict__ W1T, ushort* __restrict__ W2T,
    float* __restrict__ tail_dst)        // d_out + B*M*COUT
{
    __shared__ float4 spos[Nn];          // 32 KB: (2px,2py,2pz,pp)
    __shared__ float  sPd[8][3][33];     // [chunk][slot][qloc] — conflict-free
    __shared__ int    sPi[8][3][33];
    __shared__ int    sIdx[32][3];
    __shared__ float  sW[32][4];

    const int bid = blockIdx.x;
    const int tid = threadIdx.x;

    if (bid >= 1024) {
        // ---------------- aux roles (no LDS use) ----------------
        const int cb = bid - 1024;
        if (cb < 4096) {
            const int q   = cb * 256 + tid;        // quad over 32768x128
            const int row = q >> 5;
            const int cq  = (q & 31) * 4;
            const float4 v = *(const float4*)(xs + (size_t)row * CSKIP + cq);
            ushort4 o; o.x = f2bf(v.x); o.y = f2bf(v.y); o.z = f2bf(v.z); o.w = f2bf(v.w);
            *(ushort4*)(Abig + (size_t)row * KTOT + CIN + cq) = o;
        } else if (cb < 4192) {
            const int q  = (cb - 4096) * 256 + tid;   // 24576 quads: n*96 + kq
            const int n  = q / 96;
            const int kq = (q % 96) * 4;
            ushort4 o;
            o.x = f2bf(W1[(size_t)(kq + 0) * HID + n]);
            o.y = f2bf(W1[(size_t)(kq + 1) * HID + n]);
            o.z = f2bf(W1[(size_t)(kq + 2) * HID + n]);
            o.w = f2bf(W1[(size_t)(kq + 3) * HID + n]);
            *(ushort4*)(W1T + (size_t)n * KTOT + kq) = o;
        } else if (cb < 4224) {
            const int q  = (cb - 4192) * 256 + tid;   // 8192 quads: n*64 + kq
            const int n  = q >> 6;
            const int kq = (q & 63) * 4;
            ushort4 o;
            o.x = f2bf(W2[(size_t)(kq + 0) * COUT + n]);
            o.y = f2bf(W2[(size_t)(kq + 1) * COUT + n]);
            o.z = f2bf(W2[(size_t)(kq + 2) * COUT + n]);
            o.w = f2bf(W2[(size_t)(kq + 3) * COUT + n]);
            *(ushort4*)(W2T + (size_t)n * HID + kq) = o;
        } else {
            const int i = (cb - 4224) * 256 + tid;
            const int nPos = Bn * Mn * 3;             // 98304
            if (i < nPos) tail_dst[i] = pos_skip[i];
            else          tail_dst[i] = (float)((i - nPos) >> 13);
        }
        return;
    }

    // ---------------- KNN role ----------------
    const int qloc   = tid & 31;
    const int chunk  = tid >> 5;
    const int blockQ = bid * 32;
    const int b      = blockQ / Mn;

    for (int i = tid; i < Nn; i += 256) {
        const float* p = pos + (size_t)(b * Nn + i) * 3;
        float p0 = p[0], p1 = p[1], p2 = p[2];
        float pp = __fadd_rn(__fadd_rn(__fmul_rn(p0, p0), __fmul_rn(p1, p1)),
                             __fmul_rn(p2, p2));
        spos[i] = make_float4(2.0f * p0, 2.0f * p1, 2.0f * p2, pp);
    }
    __syncthreads();

    const int q = blockQ + qloc;
    const float* qp = pos_skip + (size_t)q * 3;
    const float q0 = qp[0], q1 = qp[1], q2 = qp[2];
    const float qq = __fadd_rn(__fadd_rn(__fmul_rn(q0, q0), __fmul_rn(q1, q1)),
                               __fmul_rn(q2, q2));

    float dA = INFINITY, dB = INFINITY, dC = INFINITY;
    int   iA = 0, iB = 0, iC = 0;
    const int base = chunk * 256;
#pragma unroll 8
    for (int j = 0; j < 256; ++j) {
        const float4 P = spos[base + j];
        const float dot2 = __fadd_rn(__fadd_rn(__fmul_rn(q0, P.x), __fmul_rn(q1, P.y)),
                                     __fmul_rn(q2, P.z));
        const float d = __fsub_rn(__fadd_rn(qq, P.w), dot2);
        const int idx = base + j;
        const bool c1 = d < dA, c2 = d < dB, c3 = d < dC;
        dC = c3 ? (c2 ? dB : d) : dC;  iC = c3 ? (c2 ? iB : idx) : iC;
        dB = c2 ? (c1 ? dA : d) : dB;  iB = c2 ? (c1 ? iA : idx) : iB;
        dA = c1 ? d : dA;              iA = c1 ? idx : iA;
    }
    sPd[chunk][0][qloc] = dA; sPd[chunk][1][qloc] = dB; sPd[chunk][2][qloc] = dC;
    sPi[chunk][0][qloc] = iA; sPi[chunk][1][qloc] = iB; sPi[chunk][2][qloc] = iC;
    __syncthreads();

    // merge 8 partial lists per query (threads 0..31), chunk order = index order
    if (tid < 32) {
        float mA = INFINITY, mB = INFINITY, mC = INFINITY;
        int   jA = 0, jB = 0, jC = 0;
#pragma unroll
        for (int c = 0; c < 8; ++c) {
#pragma unroll
            for (int s = 0; s < 3; ++s) {
                const float d = sPd[c][s][tid];
                const int   i = sPi[c][s][tid];
                const bool c1 = d < mA, c2 = d < mB, c3 = d < mC;
                mC = c3 ? (c2 ? mB : d) : mC;  jC = c3 ? (c2 ? jB : i) : jC;
                mB = c2 ? (c1 ? mA : d) : mB;  jB = c2 ? (c1 ? jA : i) : jB;
                mA = c1 ? d : mA;              jA = c1 ? i : jA;
            }
        }
        const float w0 = 1.0f / (fmaxf(mA, 0.0f) + 1e-16f);
        const float w1 = 1.0f / (fmaxf(mB, 0.0f) + 1e-16f);
        const float w2 = 1.0f / (fmaxf(mC, 0.0f) + 1e-16f);
        sIdx[tid][0] = jA; sIdx[tid][1] = jB; sIdx[tid][2] = jC;
        sW[tid][0] = w0; sW[tid][1] = w1; sW[tid][2] = w2;
        sW[tid][3] = w0 + w1 + w2;
    }
    __syncthreads();

    // gather: wave w handles queries [w*8, w*8+8); lane covers 4 channels
    const int wave = tid >> 6, lane = tid & 63;
    const size_t xbase = (size_t)b * Nn * CIN;
    for (int j = 0; j < 8; ++j) {
        const int lq = wave * 8 + j;
        const int gq = blockQ + lq;
        const int i0 = sIdx[lq][0], i1 = sIdx[lq][1], i2 = sIdx[lq][2];
        const float w0 = sW[lq][0], w1 = sW[lq][1], w2 = sW[lq][2], den = sW[lq][3];
        const float4 f0 = ((const float4*)(x + xbase + (size_t)i0 * CIN))[lane];
        const float4 f1 = ((const float4*)(x + xbase + (size_t)i1 * CIN))[lane];
        const float4 f2 = ((const float4*)(x + xbase + (size_t)i2 * CIN))[lane];
        ushort4 ov;
        ov.x = f2bf((w0 * f0.x + w1 * f1.x + w2 * f2.x) / den);
        ov.y = f2bf((w0 * f0.y + w1 * f1.y + w2 * f2.y) / den);
        ov.z = f2bf((w0 * f0.z + w1 * f1.z + w2 * f2.z) / den);
        ov.w = f2bf((w0 * f0.w + w1 * f1.w + w2 * f2.w) / den);
        *(ushort4*)(Abig + (size_t)gq * KTOT + lane * 4) = ov;
    }
}

// ---------------------------------------------------------------------------
// Kernel 2: fused MLP via bf16 MFMA (32x32x16), f32 accum. (unchanged from R3)
// ---------------------------------------------------------------------------
__global__ __launch_bounds__(256, 1) void mlp_fused(
    const ushort* __restrict__ Abig,   // [32768][384] bf16
    const ushort* __restrict__ W1T,    // [256][384] bf16
    const float*  __restrict__ b1,
    const ushort* __restrict__ W2T,    // [128][256] bf16
    const float*  __restrict__ b2,
    float* __restrict__ out)           // [32768][128] f32
{
    __shared__ ushort Ast[128 * 32];   // 8 KB
    __shared__ ushort Bst[128 * 32];   // 8 KB
    __shared__ ushort Hs [128 * 128];  // 32 KB

    const int tid  = threadIdx.x;
    const int wave = tid >> 6, lane = tid & 63;
    const int wr = wave >> 1, wc = wave & 1;      // 2x2 wave grid
    const int l31 = lane & 31, kc0 = lane >> 5;   // MFMA k-half
    const long rowbase = (long)blockIdx.x * 128;

    const int sr0 = tid >> 2;          // staging row (row+64 for 2nd chunk)
    const int ss0 = tid & 3;           // 16B slot
    const int ssw = (ss0 ^ (sr0 & 3)); // swizzled slot

    f32x16 acc2[2][2];
#pragma unroll
    for (int i = 0; i < 2; ++i)
#pragma unroll
        for (int j = 0; j < 2; ++j)
#pragma unroll
            for (int e = 0; e < 16; ++e) acc2[i][j][e] = 0.0f;

    for (int nh = 0; nh < 2; ++nh) {
        f32x16 acc1[2][2];
#pragma unroll
        for (int i = 0; i < 2; ++i)
#pragma unroll
            for (int j = 0; j < 2; ++j)
#pragma unroll
                for (int e = 0; e < 16; ++e) acc1[i][j][e] = 0.0f;

        const ushort* Ab = Abig + (size_t)rowbase * KTOT;
        const ushort* Wb = W1T + (size_t)(nh * 128) * KTOT;

        uint4 ra0, ra1, rb0, rb1;
        ra0 = *(const uint4*)(Ab + (size_t)sr0 * KTOT + ss0 * 8);
        ra1 = *(const uint4*)(Ab + (size_t)(sr0 + 64) * KTOT + ss0 * 8);
        rb0 = *(const uint4*)(Wb + (size_t)sr0 * KTOT + ss0 * 8);
        rb1 = *(const uint4*)(Wb + (size_t)(sr0 + 64) * KTOT + ss0 * 8);

        for (int t = 0; t < 12; ++t) {
            __syncthreads();
            *(uint4*)&Ast[sr0 * 32 + (ssw << 3)]        = ra0;
            *(uint4*)&Ast[(sr0 + 64) * 32 + (ssw << 3)] = ra1;
            *(uint4*)&Bst[sr0 * 32 + (ssw << 3)]        = rb0;
            *(uint4*)&Bst[(sr0 + 64) * 32 + (ssw << 3)] = rb1;
            __syncthreads();
            if (t < 11) {
                const int kt = (t + 1) * 32;
                ra0 = *(const uint4*)(Ab + (size_t)sr0 * KTOT + kt + ss0 * 8);
                ra1 = *(const uint4*)(Ab + (size_t)(sr0 + 64) * KTOT + kt + ss0 * 8);
                rb0 = *(const uint4*)(Wb + (size_t)sr0 * KTOT + kt + ss0 * 8);
                rb1 = *(const uint4*)(Wb + (size_t)(sr0 + 64) * KTOT + kt + ss0 * 8);
            }
#pragma unroll
            for (int s = 0; s < 2; ++s) {
                bf16x8 af[2], bq[2];
#pragma unroll
                for (int mf = 0; mf < 2; ++mf) {
                    const int r = wr * 64 + mf * 32 + l31;
                    af[mf] = *(const bf16x8*)&Ast[r * 32 + ((((s << 1) | kc0) ^ (r & 3)) << 3)];
                }
#pragma unroll
                for (int nf = 0; nf < 2; ++nf) {
                    const int rn = wc * 64 + nf * 32 + l31;
                    bq[nf] = *(const bf16x8*)&Bst[rn * 32 + ((((s << 1) | kc0) ^ (rn & 3)) << 3)];
                }
#pragma unroll
                for (int mf = 0; mf < 2; ++mf)
#pragma unroll
                    for (int nf = 0; nf < 2; ++nf)
                        acc1[mf][nf] = __builtin_amdgcn_mfma_f32_32x32x16_bf16(
                            af[mf], bq[nf], acc1[mf][nf], 0, 0, 0);
            }
        }

#pragma unroll
        for (int mf = 0; mf < 2; ++mf)
#pragma unroll
            for (int nf = 0; nf < 2; ++nf) {
                const int col = wc * 64 + nf * 32 + l31;
                const float b1v = b1[nh * 128 + col];
#pragma unroll
                for (int e = 0; e < 16; ++e) {
                    const int rl = wr * 64 + mf * 32 + (e & 3) + ((e >> 2) << 3) + (kc0 << 2);
                    const float hv = fmaxf(acc1[mf][nf][e] + b1v, 0.0f);
                    Hs[rl * 128 + (((col >> 3) ^ (rl & 7)) << 3) + (col & 7)] = f2bf(hv);
                }
            }
        __syncthreads();

        uint4 rw0, rw1;
        rw0 = *(const uint4*)(W2T + (size_t)sr0 * HID + nh * 128 + ss0 * 8);
        rw1 = *(const uint4*)(W2T + (size_t)(sr0 + 64) * HID + nh * 128 + ss0 * 8);

        for (int t = 0; t < 4; ++t) {
            __syncthreads();
            *(uint4*)&Bst[sr0 * 32 + (ssw << 3)]        = rw0;
            *(uint4*)&Bst[(sr0 + 64) * 32 + (ssw << 3)] = rw1;
            __syncthreads();
            if (t < 3) {
                const int kt = nh * 128 + (t + 1) * 32;
                rw0 = *(const uint4*)(W2T + (size_t)sr0 * HID + kt + ss0 * 8);
                rw1 = *(const uint4*)(W2T + (size_t)(sr0 + 64) * HID + kt + ss0 * 8);
            }
#pragma unroll
            for (int s = 0; s < 2; ++s) {
                bf16x8 af[2], bq[2];
#pragma unroll
                for (int mf = 0; mf < 2; ++mf) {
                    const int r  = wr * 64 + mf * 32 + l31;
                    const int kc = (t << 2) + (s << 1) + kc0;
                    af[mf] = *(const bf16x8*)&Hs[r * 128 + ((kc ^ (r & 7)) << 3)];
                }
#pragma unroll
                for (int nf = 0; nf < 2; ++nf) {
                    const int rn = wc * 64 + nf * 32 + l31;
                    bq[nf] = *(const bf16x8*)&Bst[rn * 32 + ((((s << 1) | kc0) ^ (rn & 3)) << 3)];
                }
#pragma unroll
                for (int mf = 0; mf < 2; ++mf)
#pragma unroll
                    for (int nf = 0; nf < 2; ++nf)
                        acc2[mf][nf] = __builtin_amdgcn_mfma_f32_32x32x16_bf16(
                            af[mf], bq[nf], acc2[mf][nf], 0, 0, 0);
            }
        }
        __syncthreads();
    }

#pragma unroll
    for (int mf = 0; mf < 2; ++mf)
#pragma unroll
        for (int nf = 0; nf < 2; ++nf) {
            const int col = wc * 64 + nf * 32 + l31;
            const float b2v = b2[col];
#pragma unroll
            for (int e = 0; e < 16; ++e) {
                const int rl = wr * 64 + mf * 32 + (e & 3) + ((e >> 2) << 3) + (kc0 << 2);
                out[(rowbase + rl) * COUT + col] = acc2[mf][nf][e] + b2v;
            }
        }
}

// ---------------------------------------------------------------------------
extern "C" void kernel_launch(void* const* d_in, const int* in_sizes, int n_in,
                              void* d_out, int out_size, void* d_ws, size_t ws_size,
                              hipStream_t stream)
{
    const float* x        = (const float*)d_in[0];
    const float* pos      = (const float*)d_in[1];
    const float* x_skip   = (const float*)d_in[2];
    const float* pos_skip = (const float*)d_in[3];
    const float* W1       = (const float*)d_in[4];
    const float* b1       = (const float*)d_in[5];
    const float* W2       = (const float*)d_in[6];
    const float* b2       = (const float*)d_in[7];

    float* out = (float*)d_out;

    // workspace: Abig (24MB) | W1T (192KB) | W2T (64KB)
    ushort* Abig = (ushort*)d_ws;
    ushort* W1T  = (ushort*)((char*)d_ws + (size_t)Bn * Mn * KTOT * 2);
    ushort* W2T  = (ushort*)((char*)W1T + (size_t)HID * KTOT * 2);

    // 1) fused front: KNN->Abig[:,0:256], x_skip->Abig[:,256:384], W1T/W2T, tail
    fused_front<<<dim3(1024 + 4224 + 512), 256, 0, stream>>>(
        x, pos, x_skip, pos_skip, W1, W2, Abig, W1T, W2T,
        out + (size_t)Bn * Mn * COUT);

    // 2) fused MLP: out = (relu([xi|x_skip] @ W1 + b1)) @ W2 + b2
    mlp_fused<<<dim3(Bn * Mn / 128), 256, 0, stream>>>(
        Abig, W1T, b1, W2T, b2, out);
}